// Round 1
// baseline (1844.136 us; speedup 1.0000x reference)
//
#include <hip/hip_runtime.h>

#define N_NODES 50000
#define N_EDGES 1600000
#define H 64
#define IN_CH 7
#define EDIM 4
#define G_GRAPHS 256
#define FC 128
#define NC 2
#define SLOPE 0.2f

__device__ __forceinline__ unsigned enc_f(float f) {
    unsigned b = __float_as_uint(f);
    return (b & 0x80000000u) ? ~b : (b | 0x80000000u);
}
__device__ __forceinline__ float dec_f(unsigned u) {
    return __uint_as_float((u & 0x80000000u) ? (u ^ 0x80000000u) : ~u);
}

// Node projection: xl = xin@Wl + bl, xr = xin@Wr + br. One thread per (n,h).
template <int K>
__global__ void proj_kernel(const float* __restrict__ xin,
                            const float* __restrict__ Wl, const float* __restrict__ bl,
                            const float* __restrict__ Wr, const float* __restrict__ br,
                            float* __restrict__ xl, float* __restrict__ xr) {
    int idx = blockIdx.x * blockDim.x + threadIdx.x;
    if (idx >= N_NODES * H) return;
    int n = idx >> 6;
    int h = idx & 63;
    const float* xi = xin + n * K;
    float al = bl[h], ar = br[h];
#pragma unroll
    for (int k = 0; k < K; ++k) {
        float xv = xi[k];
        al += xv * Wl[k * H + h];
        ar += xv * Wr[k * H + h];
    }
    xl[idx] = al;
    xr[idx] = ar;
}

// Edge pass A: one wave (64 lanes) per edge. score[e] = dot(leaky_relu(e_vec), att);
// atomicMax per-dst max (order-preserving uint encoding).
__global__ void edge_score_kernel(const int* __restrict__ src_idx, const int* __restrict__ dst_idx,
                                  const float* __restrict__ edge_attr,
                                  const float* __restrict__ xl, const float* __restrict__ xr,
                                  const float* __restrict__ We, const float* __restrict__ att,
                                  float* __restrict__ score, unsigned* __restrict__ m_enc) {
    int t = blockIdx.x * blockDim.x + threadIdx.x;
    int e = t >> 6;
    if (e >= N_EDGES) return;
    int lane = threadIdx.x & 63;
    int s = src_idx[e], d = dst_idx[e];
    float v = xl[s * H + lane] + xr[d * H + lane];
    const float* ea = edge_attr + e * EDIM;
    v += ea[0] * We[lane] + ea[1] * We[H + lane] + ea[2] * We[2 * H + lane] + ea[3] * We[3 * H + lane];
    v = v > 0.f ? v : SLOPE * v;
    float sc = v * att[lane];
#pragma unroll
    for (int off = 32; off >= 1; off >>= 1) sc += __shfl_xor(sc, off, 64);
    if (lane == 0) {
        score[e] = sc;
        atomicMax(m_enc + d, enc_f(sc));
    }
}

// Edge pass B: ex = exp(score - m[dst]); den[dst] += ex; out[dst] += ex * xl[src].
// (division by den deferred to finalize -- algebraically identical to alpha-weighting)
__global__ void edge_accum_kernel(const int* __restrict__ src_idx, const int* __restrict__ dst_idx,
                                  const float* __restrict__ xl,
                                  const float* __restrict__ score, const unsigned* __restrict__ m_enc,
                                  float* __restrict__ den, float* __restrict__ outacc) {
    int t = blockIdx.x * blockDim.x + threadIdx.x;
    int e = t >> 6;
    if (e >= N_EDGES) return;
    int lane = threadIdx.x & 63;
    int s = src_idx[e], d = dst_idx[e];
    float ex = expf(score[e] - dec_f(m_enc[d]));
    if (lane == 0) atomicAdd(den + d, ex);
    atomicAdd(outacc + d * H + lane, ex * xl[s * H + lane]);
}

// Node finalize: h = elu(acc/(den+1e-16) + bias), in place.
__global__ void finalize_kernel(const float* __restrict__ den, const float* __restrict__ bias,
                                float* __restrict__ h_inout) {
    int idx = blockIdx.x * blockDim.x + threadIdx.x;
    if (idx >= N_NODES * H) return;
    int n = idx >> 6;
    int hh = idx & 63;
    float o = h_inout[idx] / (den[n] + 1e-16f) + bias[hh];
    h_inout[idx] = o > 0.f ? o : expm1f(o);
}

// Global mean-pool (atomic accumulate): pool[g] += h[n], cnt[g] += 1.
__global__ void pool_kernel(const float* __restrict__ h, const int* __restrict__ batch,
                            float* __restrict__ pool, float* __restrict__ cnt) {
    int idx = blockIdx.x * blockDim.x + threadIdx.x;
    if (idx >= N_NODES * H) return;
    int n = idx >> 6;
    int hh = idx & 63;
    int g = batch[n];
    atomicAdd(pool + g * H + hh, h[idx]);
    if (hh == 0) atomicAdd(cnt + g, 1.f);
}

// Head: one block per graph. g -> fc1(relu) -> fc2 -> log_softmax.
__global__ void head_kernel(const float* __restrict__ pool, const float* __restrict__ cnt,
                            const float* __restrict__ fc1w, const float* __restrict__ fc1b,
                            const float* __restrict__ fc2w, const float* __restrict__ fc2b,
                            float* __restrict__ out) {
    __shared__ float g[H];
    __shared__ float f[FC];
    __shared__ float lg[NC];
    int b = blockIdx.x, t = threadIdx.x;
    if (t < H) g[t] = pool[b * H + t] / fmaxf(cnt[b], 1.f);
    __syncthreads();
    float acc = fc1b[t];
    for (int k = 0; k < H; ++k) acc += g[k] * fc1w[k * FC + t];
    f[t] = fmaxf(acc, 0.f);
    __syncthreads();
    if (t < NC) {
        float a = fc2b[t];
        for (int k = 0; k < FC; ++k) a += f[k] * fc2w[k * NC + t];
        lg[t] = a;
    }
    __syncthreads();
    if (t < NC) {
        float m = fmaxf(lg[0], lg[1]);
        float lse = m + logf(expf(lg[0] - m) + expf(lg[1] - m));
        out[b * NC + t] = lg[t] - lse;
    }
}

extern "C" void kernel_launch(void* const* d_in, const int* in_sizes, int n_in,
                              void* d_out, int out_size, void* d_ws, size_t ws_size,
                              hipStream_t stream) {
    const float* x         = (const float*)d_in[0];
    const int*   edge_idx  = (const int*)d_in[1];
    const float* edge_attr = (const float*)d_in[2];
    const int*   batch     = (const int*)d_in[3];
    const float* Wl0  = (const float*)d_in[4];
    const float* bl0  = (const float*)d_in[5];
    const float* Wr0  = (const float*)d_in[6];
    const float* br0  = (const float*)d_in[7];
    const float* We0  = (const float*)d_in[8];
    const float* att0 = (const float*)d_in[9];
    const float* bias0= (const float*)d_in[10];
    const float* Wl1  = (const float*)d_in[11];
    const float* bl1  = (const float*)d_in[12];
    const float* Wr1  = (const float*)d_in[13];
    const float* br1  = (const float*)d_in[14];
    const float* We1  = (const float*)d_in[15];
    const float* att1 = (const float*)d_in[16];
    const float* bias1= (const float*)d_in[17];
    const float* fc1w = (const float*)d_in[18];
    const float* fc1b = (const float*)d_in[19];
    const float* fc2w = (const float*)d_in[20];
    const float* fc2b = (const float*)d_in[21];

    const int NH = N_NODES * H;
    float* A     = (float*)d_ws;          // xl  [N,H]
    float* B     = A + NH;                // xr  [N,H]
    float* C     = B + NH;                // h / accumulator [N,H]
    float* den   = C + NH;                // [N]   (contiguous with C for one memset)
    unsigned* m_enc = (unsigned*)(den + N_NODES); // [N]
    float* score = (float*)(m_enc + N_NODES);     // [E]
    float* pool  = score + N_EDGES;       // [G,H]
    float* cnt   = pool + G_GRAPHS * H;   // [G]

    const int* src = edge_idx;            // edge_index[0]
    const int* dst = edge_idx + N_EDGES;  // edge_index[1]

    const int nodeBlocks = (NH + 255) / 256;
    const int edgeBlocks = (N_EDGES * 64 + 255) / 256;  // one wave per edge

    // ---------------- layer 0 ----------------
    proj_kernel<IN_CH><<<nodeBlocks, 256, 0, stream>>>(x, Wl0, bl0, Wr0, br0, A, B);
    hipMemsetAsync(C, 0, (size_t)(NH + 2 * N_NODES) * sizeof(float), stream); // C, den, m_enc
    edge_score_kernel<<<edgeBlocks, 256, 0, stream>>>(src, dst, edge_attr, A, B, We0, att0, score, m_enc);
    edge_accum_kernel<<<edgeBlocks, 256, 0, stream>>>(src, dst, A, score, m_enc, den, C);
    finalize_kernel<<<nodeBlocks, 256, 0, stream>>>(den, bias0, C);

    // ---------------- layer 1 ----------------
    proj_kernel<H><<<nodeBlocks, 256, 0, stream>>>(C, Wl1, bl1, Wr1, br1, A, B);
    hipMemsetAsync(C, 0, (size_t)(NH + 2 * N_NODES) * sizeof(float), stream);
    edge_score_kernel<<<edgeBlocks, 256, 0, stream>>>(src, dst, edge_attr, A, B, We1, att1, score, m_enc);
    edge_accum_kernel<<<edgeBlocks, 256, 0, stream>>>(src, dst, A, score, m_enc, den, C);
    finalize_kernel<<<nodeBlocks, 256, 0, stream>>>(den, bias1, C);

    // ---------------- pool + head ----------------
    hipMemsetAsync(pool, 0, (size_t)(G_GRAPHS * H + G_GRAPHS) * sizeof(float), stream);
    pool_kernel<<<nodeBlocks, 256, 0, stream>>>(C, batch, pool, cnt);
    head_kernel<<<G_GRAPHS, FC, 0, stream>>>(pool, cnt, fc1w, fc1b, fc2w, fc2b, (float*)d_out);
}

// Round 2
// 1195.094 us; speedup vs baseline: 1.5431x; 1.5431x over previous
//
#include <hip/hip_runtime.h>

#define N_NODES 50000
#define N_EDGES 1600000
#define H 64
#define IN_CH 7
#define EDIM 4
#define G_GRAPHS 256
#define FC 128
#define NC 2
#define SLOPE 0.2f

// ---------------- CSR build (once per call; reused by both layers) ----------------

__global__ void hist_kernel(const int* __restrict__ dst, int* __restrict__ deg) {
    int e = blockIdx.x * blockDim.x + threadIdx.x;
    if (e < N_EDGES) atomicAdd(&deg[dst[e]], 1);
}

// Single-block exclusive scan over deg[N] -> row_start[N+1]; also seeds cursor.
__global__ void scan_kernel(const int* __restrict__ deg, int* __restrict__ row_start,
                            int* __restrict__ cursor) {
    __shared__ int part[1024];
    const int t = threadIdx.x;
    const int CH = (N_NODES + 1023) / 1024;
    const int base = t * CH;
    int s = 0;
    for (int i = 0; i < CH; ++i) {
        int idx = base + i;
        if (idx < N_NODES) s += deg[idx];
    }
    part[t] = s;
    __syncthreads();
    for (int off = 1; off < 1024; off <<= 1) {
        int v = (t >= off) ? part[t - off] : 0;
        __syncthreads();
        part[t] += v;
        __syncthreads();
    }
    int excl = (t == 0) ? 0 : part[t - 1];
    for (int i = 0; i < CH; ++i) {
        int idx = base + i;
        if (idx < N_NODES) {
            row_start[idx] = excl;
            cursor[idx] = excl;
            excl += deg[idx];
        }
    }
    if (t == 1023) row_start[N_NODES] = part[1023];
}

__global__ void scatter_kernel(const int* __restrict__ src, const int* __restrict__ dst,
                               int* __restrict__ cursor,
                               int* __restrict__ csr_src, int* __restrict__ csr_eid) {
    int e = blockIdx.x * blockDim.x + threadIdx.x;
    if (e >= N_EDGES) return;
    int d = dst[e];
    int slot = atomicAdd(&cursor[d], 1);
    csr_src[slot] = src[e];
    csr_eid[slot] = e;
}

// ---------------- node projection ----------------
template <int K>
__global__ void proj_kernel(const float* __restrict__ xin,
                            const float* __restrict__ Wl, const float* __restrict__ bl,
                            const float* __restrict__ Wr, const float* __restrict__ br,
                            float* __restrict__ xl, float* __restrict__ xr) {
    int idx = blockIdx.x * blockDim.x + threadIdx.x;
    if (idx >= N_NODES * H) return;
    int n = idx >> 6;
    int h = idx & 63;
    const float* xi = xin + n * K;
    float al = bl[h], ar = br[h];
#pragma unroll
    for (int k = 0; k < K; ++k) {
        float xv = xi[k];
        al += xv * Wl[k * H + h];
        ar += xv * Wr[k * H + h];
    }
    xl[idx] = al;
    xr[idx] = ar;
}

// ---------------- fused GAT aggregation: one wave per dst node ----------------
// Walks the dst's incoming-edge list; computes score in-register (leaky_relu +
// shuffle-reduce dot with att), online softmax, accumulates ex*xl[src] in
// registers, then fuses den-division + bias + ELU into the epilogue.
__global__ void gat_gather_kernel(const int* __restrict__ row_start,
                                  const int* __restrict__ csr_src,
                                  const int* __restrict__ csr_eid,
                                  const float* __restrict__ edge_attr,
                                  const float* __restrict__ xl, const float* __restrict__ xr,
                                  const float* __restrict__ We, const float* __restrict__ att,
                                  const float* __restrict__ bias,
                                  float* __restrict__ out) {
    int wave = (blockIdx.x * blockDim.x + threadIdx.x) >> 6;
    if (wave >= N_NODES) return;
    int lane = threadIdx.x & 63;
    int d = wave;
    float xr_d = xr[d * H + lane];
    float attv = att[lane];
    float we0 = We[lane], we1 = We[H + lane], we2 = We[2 * H + lane], we3 = We[3 * H + lane];
    int beg = row_start[d], end = row_start[d + 1];
    float m = -INFINITY, l = 0.f, acc = 0.f;
    for (int i = beg; i < end; ++i) {
        int s = csr_src[i];
        int e = csr_eid[i];
        float4 ea = ((const float4*)edge_attr)[e];
        float xlv = xl[s * H + lane];
        float v = xlv + xr_d + ea.x * we0 + ea.y * we1 + ea.z * we2 + ea.w * we3;
        v = v > 0.f ? v : SLOPE * v;
        float sc = v * attv;
#pragma unroll
        for (int off = 32; off >= 1; off >>= 1) sc += __shfl_xor(sc, off, 64);
        float mn = fmaxf(m, sc);
        float corr = __expf(m - mn);   // first iter: exp(-inf)=0 zeroes the empty state
        float p = __expf(sc - mn);
        l = l * corr + p;
        acc = acc * corr + p * xlv;
        m = mn;
    }
    float o = acc / (l + 1e-16f) + bias[lane];
    out[d * H + lane] = o > 0.f ? o : expm1f(o);
}

// ---------------- pool + head ----------------
__global__ void pool_kernel(const float* __restrict__ h, const int* __restrict__ batch,
                            float* __restrict__ pool, float* __restrict__ cnt) {
    int idx = blockIdx.x * blockDim.x + threadIdx.x;
    if (idx >= N_NODES * H) return;
    int n = idx >> 6;
    int hh = idx & 63;
    int g = batch[n];
    atomicAdd(pool + g * H + hh, h[idx]);
    if (hh == 0) atomicAdd(cnt + g, 1.f);
}

__global__ void head_kernel(const float* __restrict__ pool, const float* __restrict__ cnt,
                            const float* __restrict__ fc1w, const float* __restrict__ fc1b,
                            const float* __restrict__ fc2w, const float* __restrict__ fc2b,
                            float* __restrict__ out) {
    __shared__ float g[H];
    __shared__ float f[FC];
    __shared__ float lg[NC];
    int b = blockIdx.x, t = threadIdx.x;
    if (t < H) g[t] = pool[b * H + t] / fmaxf(cnt[b], 1.f);
    __syncthreads();
    float acc = fc1b[t];
    for (int k = 0; k < H; ++k) acc += g[k] * fc1w[k * FC + t];
    f[t] = fmaxf(acc, 0.f);
    __syncthreads();
    if (t < NC) {
        float a = fc2b[t];
        for (int k = 0; k < FC; ++k) a += f[k] * fc2w[k * NC + t];
        lg[t] = a;
    }
    __syncthreads();
    if (t < NC) {
        float mx = fmaxf(lg[0], lg[1]);
        float lse = mx + logf(expf(lg[0] - mx) + expf(lg[1] - mx));
        out[b * NC + t] = lg[t] - lse;
    }
}

extern "C" void kernel_launch(void* const* d_in, const int* in_sizes, int n_in,
                              void* d_out, int out_size, void* d_ws, size_t ws_size,
                              hipStream_t stream) {
    const float* x         = (const float*)d_in[0];
    const int*   edge_idx  = (const int*)d_in[1];
    const float* edge_attr = (const float*)d_in[2];
    const int*   batch     = (const int*)d_in[3];
    const float* Wl0  = (const float*)d_in[4];
    const float* bl0  = (const float*)d_in[5];
    const float* Wr0  = (const float*)d_in[6];
    const float* br0  = (const float*)d_in[7];
    const float* We0  = (const float*)d_in[8];
    const float* att0 = (const float*)d_in[9];
    const float* bias0= (const float*)d_in[10];
    const float* Wl1  = (const float*)d_in[11];
    const float* bl1  = (const float*)d_in[12];
    const float* Wr1  = (const float*)d_in[13];
    const float* br1  = (const float*)d_in[14];
    const float* We1  = (const float*)d_in[15];
    const float* att1 = (const float*)d_in[16];
    const float* bias1= (const float*)d_in[17];
    const float* fc1w = (const float*)d_in[18];
    const float* fc1b = (const float*)d_in[19];
    const float* fc2w = (const float*)d_in[20];
    const float* fc2b = (const float*)d_in[21];

    const int NH = N_NODES * H;
    float* A        = (float*)d_ws;            // xl [N,H]
    float* B        = A + NH;                  // xr [N,H]
    float* C        = B + NH;                  // layer output [N,H]
    int*   deg      = (int*)(C + NH);          // [N]
    int*   row_start= deg + N_NODES;           // [N+1]
    int*   cursor   = row_start + N_NODES + 1; // [N]
    int*   csr_src  = cursor + N_NODES;        // [E]
    int*   csr_eid  = csr_src + N_EDGES;       // [E]
    float* pool     = (float*)(csr_eid + N_EDGES); // [G,H]
    float* cnt      = pool + G_GRAPHS * H;     // [G]

    const int* src = edge_idx;
    const int* dst = edge_idx + N_EDGES;

    const int nodeBlocks = (NH + 255) / 256;
    const int edgeBlocks = (N_EDGES + 255) / 256;
    const int waveBlocks = (N_NODES * 64 + 255) / 256;  // one wave per dst node

    // ---- CSR build (used by both layers) ----
    hipMemsetAsync(deg, 0, (size_t)N_NODES * sizeof(int), stream);
    hist_kernel<<<edgeBlocks, 256, 0, stream>>>(dst, deg);
    scan_kernel<<<1, 1024, 0, stream>>>(deg, row_start, cursor);
    scatter_kernel<<<edgeBlocks, 256, 0, stream>>>(src, dst, cursor, csr_src, csr_eid);

    // ---- layer 0 ----
    proj_kernel<IN_CH><<<nodeBlocks, 256, 0, stream>>>(x, Wl0, bl0, Wr0, br0, A, B);
    gat_gather_kernel<<<waveBlocks, 256, 0, stream>>>(row_start, csr_src, csr_eid, edge_attr,
                                                      A, B, We0, att0, bias0, C);

    // ---- layer 1 ----
    proj_kernel<H><<<nodeBlocks, 256, 0, stream>>>(C, Wl1, bl1, Wr1, br1, A, B);
    gat_gather_kernel<<<waveBlocks, 256, 0, stream>>>(row_start, csr_src, csr_eid, edge_attr,
                                                      A, B, We1, att1, bias1, C);

    // ---- pool + head ----
    hipMemsetAsync(pool, 0, (size_t)(G_GRAPHS * H + G_GRAPHS) * sizeof(float), stream);
    pool_kernel<<<nodeBlocks, 256, 0, stream>>>(C, batch, pool, cnt);
    head_kernel<<<G_GRAPHS, FC, 0, stream>>>(pool, cnt, fc1w, fc1b, fc2w, fc2b, (float*)d_out);
}

// Round 3
// 931.844 us; speedup vs baseline: 1.9790x; 1.2825x over previous
//
#include <hip/hip_runtime.h>

#define N_NODES 50000
#define N_EDGES 1600000
#define H 64
#define IN_CH 7
#define EDIM 4
#define G_GRAPHS 256
#define FC 128
#define NC 2
#define SLOPE 0.2f

// ---------------- DPP wave-64 reductions (no LDS pipe, VALU-speed) ----------------
// sum: bound_ctrl=true -> OOB lanes contribute 0. Result valid in lane 63.
__device__ __forceinline__ float wave_sum_to63(float x) {
    x += __int_as_float(__builtin_amdgcn_update_dpp(0, __float_as_int(x), 0x111, 0xf, 0xf, true)); // row_shr:1
    x += __int_as_float(__builtin_amdgcn_update_dpp(0, __float_as_int(x), 0x112, 0xf, 0xf, true)); // row_shr:2
    x += __int_as_float(__builtin_amdgcn_update_dpp(0, __float_as_int(x), 0x114, 0xf, 0xf, true)); // row_shr:4
    x += __int_as_float(__builtin_amdgcn_update_dpp(0, __float_as_int(x), 0x118, 0xf, 0xf, true)); // row_shr:8
    x += __int_as_float(__builtin_amdgcn_update_dpp(0, __float_as_int(x), 0x142, 0xf, 0xf, true)); // row_bcast:15
    x += __int_as_float(__builtin_amdgcn_update_dpp(0, __float_as_int(x), 0x143, 0xf, 0xf, true)); // row_bcast:31
    return x;
}
// max: bound_ctrl=false, old=x -> OOB lanes see x (identity for max). Result in lane 63.
__device__ __forceinline__ float wave_max_to63(float x) {
    int xi = __float_as_int(x);
    x = fmaxf(x, __int_as_float(__builtin_amdgcn_update_dpp(xi, xi, 0x111, 0xf, 0xf, false))); xi = __float_as_int(x);
    x = fmaxf(x, __int_as_float(__builtin_amdgcn_update_dpp(xi, xi, 0x112, 0xf, 0xf, false))); xi = __float_as_int(x);
    x = fmaxf(x, __int_as_float(__builtin_amdgcn_update_dpp(xi, xi, 0x114, 0xf, 0xf, false))); xi = __float_as_int(x);
    x = fmaxf(x, __int_as_float(__builtin_amdgcn_update_dpp(xi, xi, 0x118, 0xf, 0xf, false))); xi = __float_as_int(x);
    x = fmaxf(x, __int_as_float(__builtin_amdgcn_update_dpp(xi, xi, 0x142, 0xf, 0xf, false))); xi = __float_as_int(x);
    x = fmaxf(x, __int_as_float(__builtin_amdgcn_update_dpp(xi, xi, 0x143, 0xf, 0xf, false)));
    return x;
}
__device__ __forceinline__ float lane63_bcast(float x) {
    return __int_as_float(__builtin_amdgcn_readlane(__float_as_int(x), 63));
}
__device__ __forceinline__ float readlane_f(float x, int i) {
    return __int_as_float(__builtin_amdgcn_readlane(__float_as_int(x), i));
}

// ---------------- CSR build (once per call; reused by both layers) ----------------
__global__ void hist_kernel(const int* __restrict__ dst, int* __restrict__ deg) {
    int e = blockIdx.x * blockDim.x + threadIdx.x;
    if (e < N_EDGES) atomicAdd(&deg[dst[e]], 1);
}

__global__ void scan_kernel(const int* __restrict__ deg, int* __restrict__ row_start,
                            int* __restrict__ cursor) {
    __shared__ int part[1024];
    const int t = threadIdx.x;
    const int CH = (N_NODES + 1023) / 1024;
    const int base = t * CH;
    int s = 0;
    for (int i = 0; i < CH; ++i) {
        int idx = base + i;
        if (idx < N_NODES) s += deg[idx];
    }
    part[t] = s;
    __syncthreads();
    for (int off = 1; off < 1024; off <<= 1) {
        int v = (t >= off) ? part[t - off] : 0;
        __syncthreads();
        part[t] += v;
        __syncthreads();
    }
    int excl = (t == 0) ? 0 : part[t - 1];
    for (int i = 0; i < CH; ++i) {
        int idx = base + i;
        if (idx < N_NODES) {
            row_start[idx] = excl;
            cursor[idx] = excl;
            excl += deg[idx];
        }
    }
    if (t == 1023) row_start[N_NODES] = part[1023];
}

__global__ void scatter_kernel(const int* __restrict__ src, const int* __restrict__ dst,
                               int* __restrict__ cursor,
                               int* __restrict__ csr_src, int* __restrict__ csr_eid) {
    int e = blockIdx.x * blockDim.x + threadIdx.x;
    if (e >= N_EDGES) return;
    int d = dst[e];
    int slot = atomicAdd(&cursor[d], 1);
    csr_src[slot] = src[e];
    csr_eid[slot] = e;
}

// ---------------- node projection ----------------
template <int K>
__global__ void proj_kernel(const float* __restrict__ xin,
                            const float* __restrict__ Wl, const float* __restrict__ bl,
                            const float* __restrict__ Wr, const float* __restrict__ br,
                            float* __restrict__ xl, float* __restrict__ xr) {
    int idx = blockIdx.x * blockDim.x + threadIdx.x;
    if (idx >= N_NODES * H) return;
    int n = idx >> 6;
    int h = idx & 63;
    const float* xi = xin + n * K;
    float al = bl[h], ar = br[h];
#pragma unroll
    for (int k = 0; k < K; ++k) {
        float xv = xi[k];
        al += xv * Wl[k * H + h];
        ar += xv * Wr[k * H + h];
    }
    xl[idx] = al;
    xr[idx] = ar;
}

// ---------------- fused GAT aggregation: one wave per dst node ----------------
// Chunked (64-edge) flash-style softmax:
//   phase 0: independent per-edge score computation (DPP reduce), lane i holds score i
//   phase 1: lane-parallel max/exp/sum (one exp instruction per chunk)
//   phase 2: independent weighted accumulation with dual accumulators
__device__ __forceinline__ float edge_score_vec(int idx, const int* __restrict__ csr_src,
                                                const int* __restrict__ csr_eid,
                                                const float* __restrict__ edge_attr,
                                                const float* __restrict__ xl,
                                                float xr_d, float we0, float we1, float we2, float we3,
                                                float attv, int lane) {
    int s = __builtin_amdgcn_readfirstlane(csr_src[idx]);
    int e = __builtin_amdgcn_readfirstlane(csr_eid[idx]);
    float4 ea = ((const float4*)edge_attr)[e];
    float v = xl[s * H + lane] + xr_d;
    v += ea.x * we0 + ea.y * we1 + ea.z * we2 + ea.w * we3;
    v = v > 0.f ? v : SLOPE * v;
    return wave_sum_to63(v * attv);   // caller reads lane 63
}

__global__ __launch_bounds__(256) void gat_gather_kernel(
        const int* __restrict__ row_start,
        const int* __restrict__ csr_src,
        const int* __restrict__ csr_eid,
        const float* __restrict__ edge_attr,
        const float* __restrict__ xl, const float* __restrict__ xr,
        const float* __restrict__ We, const float* __restrict__ att,
        const float* __restrict__ bias,
        float* __restrict__ out) {
    int wave = (blockIdx.x * blockDim.x + threadIdx.x) >> 6;
    if (wave >= N_NODES) return;
    int lane = threadIdx.x & 63;
    int d = wave;
    float xr_d = xr[d * H + lane];
    float attv = att[lane];
    float we0 = We[lane], we1 = We[H + lane], we2 = We[2 * H + lane], we3 = We[3 * H + lane];
    int beg = __builtin_amdgcn_readfirstlane(row_start[d]);
    int end = __builtin_amdgcn_readfirstlane(row_start[d + 1]);

    float m_run = -INFINITY, l_run = 0.f;
    float acc0 = 0.f, acc1 = 0.f;

    for (int cbeg = beg; cbeg < end; cbeg += 64) {
        int n = min(64, end - cbeg);

        // ---- phase 0: scores; lane i keeps score of edge cbeg+i ----
        float scv = -INFINITY;
        int i = 0;
        for (; i + 4 <= n; i += 4) {
            float r0 = edge_score_vec(cbeg + i + 0, csr_src, csr_eid, edge_attr, xl, xr_d, we0, we1, we2, we3, attv, lane);
            float r1 = edge_score_vec(cbeg + i + 1, csr_src, csr_eid, edge_attr, xl, xr_d, we0, we1, we2, we3, attv, lane);
            float r2 = edge_score_vec(cbeg + i + 2, csr_src, csr_eid, edge_attr, xl, xr_d, we0, we1, we2, we3, attv, lane);
            float r3 = edge_score_vec(cbeg + i + 3, csr_src, csr_eid, edge_attr, xl, xr_d, we0, we1, we2, we3, attv, lane);
            float s0 = lane63_bcast(r0), s1 = lane63_bcast(r1), s2 = lane63_bcast(r2), s3 = lane63_bcast(r3);
            scv = (lane == i + 0) ? s0 : scv;
            scv = (lane == i + 1) ? s1 : scv;
            scv = (lane == i + 2) ? s2 : scv;
            scv = (lane == i + 3) ? s3 : scv;
        }
        for (; i < n; ++i) {
            float r0 = edge_score_vec(cbeg + i, csr_src, csr_eid, edge_attr, xl, xr_d, we0, we1, we2, we3, attv, lane);
            float s0 = lane63_bcast(r0);
            scv = (lane == i) ? s0 : scv;
        }

        // ---- phase 1: lane-parallel softmax pieces ----
        float m_chunk = lane63_bcast(wave_max_to63(scv));
        float m_new = fmaxf(m_run, m_chunk);
        float corr = __expf(m_run - m_new);          // first chunk: exp(-inf)=0
        float p = __expf(scv - m_new);               // lanes >= n: exp(-inf)=0
        float psum = lane63_bcast(wave_sum_to63(p));
        l_run = l_run * corr + psum;
        acc0 *= corr;
        acc1 *= corr;
        m_run = m_new;

        // ---- phase 2: weighted accumulation (independent iterations) ----
        i = 0;
        for (; i + 4 <= n; i += 4) {
            int s0 = __builtin_amdgcn_readfirstlane(csr_src[cbeg + i + 0]);
            int s1 = __builtin_amdgcn_readfirstlane(csr_src[cbeg + i + 1]);
            int s2 = __builtin_amdgcn_readfirstlane(csr_src[cbeg + i + 2]);
            int s3 = __builtin_amdgcn_readfirstlane(csr_src[cbeg + i + 3]);
            float p0 = readlane_f(p, i + 0);
            float p1 = readlane_f(p, i + 1);
            float p2 = readlane_f(p, i + 2);
            float p3 = readlane_f(p, i + 3);
            acc0 += p0 * xl[s0 * H + lane];
            acc1 += p1 * xl[s1 * H + lane];
            acc0 += p2 * xl[s2 * H + lane];
            acc1 += p3 * xl[s3 * H + lane];
        }
        for (; i < n; ++i) {
            int s0 = __builtin_amdgcn_readfirstlane(csr_src[cbeg + i]);
            float p0 = readlane_f(p, i);
            acc0 += p0 * xl[s0 * H + lane];
        }
    }

    float o = (acc0 + acc1) / (l_run + 1e-16f) + bias[lane];
    out[d * H + lane] = o > 0.f ? o : expm1f(o);
}

// ---------------- pool + head ----------------
__global__ void pool_kernel(const float* __restrict__ h, const int* __restrict__ batch,
                            float* __restrict__ pool, float* __restrict__ cnt) {
    int idx = blockIdx.x * blockDim.x + threadIdx.x;
    if (idx >= N_NODES * H) return;
    int n = idx >> 6;
    int hh = idx & 63;
    int g = batch[n];
    atomicAdd(pool + g * H + hh, h[idx]);
    if (hh == 0) atomicAdd(cnt + g, 1.f);
}

__global__ void head_kernel(const float* __restrict__ pool, const float* __restrict__ cnt,
                            const float* __restrict__ fc1w, const float* __restrict__ fc1b,
                            const float* __restrict__ fc2w, const float* __restrict__ fc2b,
                            float* __restrict__ out) {
    __shared__ float g[H];
    __shared__ float f[FC];
    __shared__ float lg[NC];
    int b = blockIdx.x, t = threadIdx.x;
    if (t < H) g[t] = pool[b * H + t] / fmaxf(cnt[b], 1.f);
    __syncthreads();
    float acc = fc1b[t];
    for (int k = 0; k < H; ++k) acc += g[k] * fc1w[k * FC + t];
    f[t] = fmaxf(acc, 0.f);
    __syncthreads();
    if (t < NC) {
        float a = fc2b[t];
        for (int k = 0; k < FC; ++k) a += f[k] * fc2w[k * NC + t];
        lg[t] = a;
    }
    __syncthreads();
    if (t < NC) {
        float mx = fmaxf(lg[0], lg[1]);
        float lse = mx + logf(expf(lg[0] - mx) + expf(lg[1] - mx));
        out[b * NC + t] = lg[t] - lse;
    }
}

extern "C" void kernel_launch(void* const* d_in, const int* in_sizes, int n_in,
                              void* d_out, int out_size, void* d_ws, size_t ws_size,
                              hipStream_t stream) {
    const float* x         = (const float*)d_in[0];
    const int*   edge_idx  = (const int*)d_in[1];
    const float* edge_attr = (const float*)d_in[2];
    const int*   batch     = (const int*)d_in[3];
    const float* Wl0  = (const float*)d_in[4];
    const float* bl0  = (const float*)d_in[5];
    const float* Wr0  = (const float*)d_in[6];
    const float* br0  = (const float*)d_in[7];
    const float* We0  = (const float*)d_in[8];
    const float* att0 = (const float*)d_in[9];
    const float* bias0= (const float*)d_in[10];
    const float* Wl1  = (const float*)d_in[11];
    const float* bl1  = (const float*)d_in[12];
    const float* Wr1  = (const float*)d_in[13];
    const float* br1  = (const float*)d_in[14];
    const float* We1  = (const float*)d_in[15];
    const float* att1 = (const float*)d_in[16];
    const float* bias1= (const float*)d_in[17];
    const float* fc1w = (const float*)d_in[18];
    const float* fc1b = (const float*)d_in[19];
    const float* fc2w = (const float*)d_in[20];
    const float* fc2b = (const float*)d_in[21];

    const int NH = N_NODES * H;
    float* A        = (float*)d_ws;            // xl [N,H]
    float* B        = A + NH;                  // xr [N,H]
    float* C        = B + NH;                  // layer output [N,H]
    int*   deg      = (int*)(C + NH);          // [N]
    int*   row_start= deg + N_NODES;           // [N+1]
    int*   cursor   = row_start + N_NODES + 1; // [N]
    int*   csr_src  = cursor + N_NODES;        // [E]
    int*   csr_eid  = csr_src + N_EDGES;       // [E]
    float* pool     = (float*)(csr_eid + N_EDGES); // [G,H]
    float* cnt      = pool + G_GRAPHS * H;     // [G]

    const int* src = edge_idx;
    const int* dst = edge_idx + N_EDGES;

    const int nodeBlocks = (NH + 255) / 256;
    const int edgeBlocks = (N_EDGES + 255) / 256;
    const int waveBlocks = (N_NODES * 64 + 255) / 256;  // one wave per dst node

    // ---- CSR build (used by both layers) ----
    hipMemsetAsync(deg, 0, (size_t)N_NODES * sizeof(int), stream);
    hist_kernel<<<edgeBlocks, 256, 0, stream>>>(dst, deg);
    scan_kernel<<<1, 1024, 0, stream>>>(deg, row_start, cursor);
    scatter_kernel<<<edgeBlocks, 256, 0, stream>>>(src, dst, cursor, csr_src, csr_eid);

    // ---- layer 0 ----
    proj_kernel<IN_CH><<<nodeBlocks, 256, 0, stream>>>(x, Wl0, bl0, Wr0, br0, A, B);
    gat_gather_kernel<<<waveBlocks, 256, 0, stream>>>(row_start, csr_src, csr_eid, edge_attr,
                                                      A, B, We0, att0, bias0, C);

    // ---- layer 1 ----
    proj_kernel<H><<<nodeBlocks, 256, 0, stream>>>(C, Wl1, bl1, Wr1, br1, A, B);
    gat_gather_kernel<<<waveBlocks, 256, 0, stream>>>(row_start, csr_src, csr_eid, edge_attr,
                                                      A, B, We1, att1, bias1, C);

    // ---- pool + head ----
    hipMemsetAsync(pool, 0, (size_t)(G_GRAPHS * H + G_GRAPHS) * sizeof(float), stream);
    pool_kernel<<<nodeBlocks, 256, 0, stream>>>(C, batch, pool, cnt);
    head_kernel<<<G_GRAPHS, FC, 0, stream>>>(pool, cnt, fc1w, fc1b, fc2w, fc2b, (float*)d_out);
}

// Round 4
// 604.834 us; speedup vs baseline: 3.0490x; 1.5407x over previous
//
#include <hip/hip_runtime.h>

#define N_NODES 50000
#define N_EDGES 1600000
#define H 64
#define IN_CH 7
#define EDIM 4
#define G_GRAPHS 256
#define FC 128
#define NC 2
#define SLOPE 0.2f
#define SCAN_BLOCKS ((N_NODES + 255) / 256)   // 196

// ---------------- DPP wave-64 reductions (no LDS pipe, VALU-speed) ----------------
__device__ __forceinline__ float wave_sum_to63(float x) {
    x += __int_as_float(__builtin_amdgcn_update_dpp(0, __float_as_int(x), 0x111, 0xf, 0xf, true)); // row_shr:1
    x += __int_as_float(__builtin_amdgcn_update_dpp(0, __float_as_int(x), 0x112, 0xf, 0xf, true)); // row_shr:2
    x += __int_as_float(__builtin_amdgcn_update_dpp(0, __float_as_int(x), 0x114, 0xf, 0xf, true)); // row_shr:4
    x += __int_as_float(__builtin_amdgcn_update_dpp(0, __float_as_int(x), 0x118, 0xf, 0xf, true)); // row_shr:8
    x += __int_as_float(__builtin_amdgcn_update_dpp(0, __float_as_int(x), 0x142, 0xf, 0xf, true)); // row_bcast:15
    x += __int_as_float(__builtin_amdgcn_update_dpp(0, __float_as_int(x), 0x143, 0xf, 0xf, true)); // row_bcast:31
    return x;
}
__device__ __forceinline__ float wave_max_to63(float x) {
    int xi = __float_as_int(x);
    x = fmaxf(x, __int_as_float(__builtin_amdgcn_update_dpp(xi, xi, 0x111, 0xf, 0xf, false))); xi = __float_as_int(x);
    x = fmaxf(x, __int_as_float(__builtin_amdgcn_update_dpp(xi, xi, 0x112, 0xf, 0xf, false))); xi = __float_as_int(x);
    x = fmaxf(x, __int_as_float(__builtin_amdgcn_update_dpp(xi, xi, 0x114, 0xf, 0xf, false))); xi = __float_as_int(x);
    x = fmaxf(x, __int_as_float(__builtin_amdgcn_update_dpp(xi, xi, 0x118, 0xf, 0xf, false))); xi = __float_as_int(x);
    x = fmaxf(x, __int_as_float(__builtin_amdgcn_update_dpp(xi, xi, 0x142, 0xf, 0xf, false))); xi = __float_as_int(x);
    x = fmaxf(x, __int_as_float(__builtin_amdgcn_update_dpp(xi, xi, 0x143, 0xf, 0xf, false)));
    return x;
}
__device__ __forceinline__ float lane63_bcast(float x) {
    return __int_as_float(__builtin_amdgcn_readlane(__float_as_int(x), 63));
}
__device__ __forceinline__ float readlane_f(float x, int i) {
    return __int_as_float(__builtin_amdgcn_readlane(__float_as_int(x), i));
}

// ---------------- CSR build ----------------
__global__ void hist_kernel(const int* __restrict__ dst, int* __restrict__ deg) {
    int e = blockIdx.x * blockDim.x + threadIdx.x;
    if (e < N_EDGES) atomicAdd(&deg[dst[e]], 1);
}

// 3-kernel parallel exclusive scan over deg[N]
__global__ void scan_part_kernel(const int* __restrict__ deg, int* __restrict__ bsum) {
    __shared__ int lds[256];
    int b = blockIdx.x, t = threadIdx.x;
    int idx = b * 256 + t;
    lds[t] = (idx < N_NODES) ? deg[idx] : 0;
    __syncthreads();
    for (int off = 128; off >= 1; off >>= 1) {
        if (t < off) lds[t] += lds[t + off];
        __syncthreads();
    }
    if (t == 0) bsum[b] = lds[0];
}

__global__ void scan_top_kernel(const int* __restrict__ bsum, int* __restrict__ boff) {
    __shared__ int lds[256];
    int t = threadIdx.x;
    int v = (t < SCAN_BLOCKS) ? bsum[t] : 0;
    lds[t] = v;
    __syncthreads();
    for (int off = 1; off < 256; off <<= 1) {
        int x = (t >= off) ? lds[t - off] : 0;
        __syncthreads();
        lds[t] += x;
        __syncthreads();
    }
    boff[t] = lds[t] - v;   // exclusive
}

__global__ void scan_final_kernel(const int* __restrict__ deg, const int* __restrict__ boff,
                                  int* __restrict__ row_start, int* __restrict__ cursor) {
    __shared__ int lds[256];
    int b = blockIdx.x, t = threadIdx.x;
    int idx = b * 256 + t;
    int v = (idx < N_NODES) ? deg[idx] : 0;
    lds[t] = v;
    __syncthreads();
    for (int off = 1; off < 256; off <<= 1) {
        int x = (t >= off) ? lds[t - off] : 0;
        __syncthreads();
        lds[t] += x;
        __syncthreads();
    }
    int excl = boff[b] + lds[t] - v;
    if (idx < N_NODES) {
        row_start[idx] = excl;
        cursor[idx] = excl;
        if (idx == N_NODES - 1) row_start[N_NODES] = excl + v;
    }
}

template <bool USE_EA>
__global__ void scatter_kernel(const int* __restrict__ src, const int* __restrict__ dst,
                               const float* __restrict__ edge_attr,
                               int* __restrict__ cursor,
                               int* __restrict__ csr_src, int* __restrict__ csr_eid,
                               float4* __restrict__ csr_ea) {
    int e = blockIdx.x * blockDim.x + threadIdx.x;
    if (e >= N_EDGES) return;
    int d = dst[e];
    int slot = atomicAdd(&cursor[d], 1);
    csr_src[slot] = src[e];
    if (USE_EA) csr_ea[slot] = ((const float4*)edge_attr)[e];
    else        csr_eid[slot] = e;
}

// ---------------- node projection ----------------
template <int K>
__global__ void proj_kernel(const float* __restrict__ xin,
                            const float* __restrict__ Wl, const float* __restrict__ bl,
                            const float* __restrict__ Wr, const float* __restrict__ br,
                            float* __restrict__ xl, float* __restrict__ xr) {
    int idx = blockIdx.x * blockDim.x + threadIdx.x;
    if (idx >= N_NODES * H) return;
    int n = idx >> 6;
    int h = idx & 63;
    const float* xi = xin + n * K;
    float al = bl[h], ar = br[h];
#pragma unroll
    for (int k = 0; k < K; ++k) {
        float xv = xi[k];
        al += xv * Wl[k * H + h];
        ar += xv * Wr[k * H + h];
    }
    xl[idx] = al;
    xr[idx] = ar;
}

// ---------------- fused GAT aggregation: one wave per dst node ----------------
__device__ __forceinline__ float score_from(int s, float4 ea, const float* __restrict__ xl,
                                            float xr_d, float we0, float we1, float we2, float we3,
                                            float attv, int lane) {
    float v = xl[s * H + lane] + xr_d;
    v += ea.x * we0 + ea.y * we1 + ea.z * we2 + ea.w * we3;
    v = v > 0.f ? v : SLOPE * v;
    return wave_sum_to63(v * attv);   // caller reads lane 63
}

template <bool USE_EA>
__global__ __launch_bounds__(256) void gat_gather_kernel(
        const int* __restrict__ row_start,
        const int* __restrict__ csr_src,
        const int* __restrict__ csr_eid,
        const float4* __restrict__ csr_ea,
        const float* __restrict__ edge_attr,
        const float* __restrict__ xl, const float* __restrict__ xr,
        const float* __restrict__ We, const float* __restrict__ att,
        const float* __restrict__ bias,
        float* __restrict__ out) {
    int wave = (blockIdx.x * blockDim.x + threadIdx.x) >> 6;
    if (wave >= N_NODES) return;
    int lane = threadIdx.x & 63;
    int d = wave;
    float xr_d = xr[d * H + lane];
    float attv = att[lane];
    float we0 = We[lane], we1 = We[H + lane], we2 = We[2 * H + lane], we3 = We[3 * H + lane];
    int beg = __builtin_amdgcn_readfirstlane(row_start[d]);
    int end = __builtin_amdgcn_readfirstlane(row_start[d + 1]);

    float m_run = -INFINITY, l_run = 0.f;
    float acc0 = 0.f, acc1 = 0.f;

    for (int cbeg = beg; cbeg < end; cbeg += 64) {
        int n = min(64, end - cbeg);

        // ---- phase 0: scores; lane i keeps score of edge cbeg+i ----
        float scv = -INFINITY;
        int i = 0;
        for (; i + 4 <= n; i += 4) {
            int s0 = __builtin_amdgcn_readfirstlane(csr_src[cbeg + i + 0]);
            int s1 = __builtin_amdgcn_readfirstlane(csr_src[cbeg + i + 1]);
            int s2 = __builtin_amdgcn_readfirstlane(csr_src[cbeg + i + 2]);
            int s3 = __builtin_amdgcn_readfirstlane(csr_src[cbeg + i + 3]);
            float4 ea0, ea1, ea2, ea3;
            if (USE_EA) {
                ea0 = csr_ea[cbeg + i + 0]; ea1 = csr_ea[cbeg + i + 1];
                ea2 = csr_ea[cbeg + i + 2]; ea3 = csr_ea[cbeg + i + 3];
            } else {
                int e0 = __builtin_amdgcn_readfirstlane(csr_eid[cbeg + i + 0]);
                int e1 = __builtin_amdgcn_readfirstlane(csr_eid[cbeg + i + 1]);
                int e2 = __builtin_amdgcn_readfirstlane(csr_eid[cbeg + i + 2]);
                int e3 = __builtin_amdgcn_readfirstlane(csr_eid[cbeg + i + 3]);
                ea0 = ((const float4*)edge_attr)[e0]; ea1 = ((const float4*)edge_attr)[e1];
                ea2 = ((const float4*)edge_attr)[e2]; ea3 = ((const float4*)edge_attr)[e3];
            }
            float r0 = score_from(s0, ea0, xl, xr_d, we0, we1, we2, we3, attv, lane);
            float r1 = score_from(s1, ea1, xl, xr_d, we0, we1, we2, we3, attv, lane);
            float r2 = score_from(s2, ea2, xl, xr_d, we0, we1, we2, we3, attv, lane);
            float r3 = score_from(s3, ea3, xl, xr_d, we0, we1, we2, we3, attv, lane);
            float b0 = lane63_bcast(r0), b1 = lane63_bcast(r1), b2 = lane63_bcast(r2), b3 = lane63_bcast(r3);
            scv = (lane == i + 0) ? b0 : scv;
            scv = (lane == i + 1) ? b1 : scv;
            scv = (lane == i + 2) ? b2 : scv;
            scv = (lane == i + 3) ? b3 : scv;
        }
        for (; i < n; ++i) {
            int s0 = __builtin_amdgcn_readfirstlane(csr_src[cbeg + i]);
            float4 ea0;
            if (USE_EA) ea0 = csr_ea[cbeg + i];
            else {
                int e0 = __builtin_amdgcn_readfirstlane(csr_eid[cbeg + i]);
                ea0 = ((const float4*)edge_attr)[e0];
            }
            float r0 = score_from(s0, ea0, xl, xr_d, we0, we1, we2, we3, attv, lane);
            float b0 = lane63_bcast(r0);
            scv = (lane == i) ? b0 : scv;
        }

        // ---- phase 1: lane-parallel softmax pieces ----
        float m_chunk = lane63_bcast(wave_max_to63(scv));
        float m_new = fmaxf(m_run, m_chunk);
        float corr = __expf(m_run - m_new);   // first chunk: exp(-inf)=0
        float p = __expf(scv - m_new);        // lanes >= n: exp(-inf)=0
        float psum = lane63_bcast(wave_sum_to63(p));
        l_run = l_run * corr + psum;
        acc0 *= corr;
        acc1 *= corr;
        m_run = m_new;

        // ---- phase 2: weighted accumulation (independent iterations) ----
        i = 0;
        for (; i + 4 <= n; i += 4) {
            int s0 = __builtin_amdgcn_readfirstlane(csr_src[cbeg + i + 0]);
            int s1 = __builtin_amdgcn_readfirstlane(csr_src[cbeg + i + 1]);
            int s2 = __builtin_amdgcn_readfirstlane(csr_src[cbeg + i + 2]);
            int s3 = __builtin_amdgcn_readfirstlane(csr_src[cbeg + i + 3]);
            float p0 = readlane_f(p, i + 0);
            float p1 = readlane_f(p, i + 1);
            float p2 = readlane_f(p, i + 2);
            float p3 = readlane_f(p, i + 3);
            acc0 += p0 * xl[s0 * H + lane];
            acc1 += p1 * xl[s1 * H + lane];
            acc0 += p2 * xl[s2 * H + lane];
            acc1 += p3 * xl[s3 * H + lane];
        }
        for (; i < n; ++i) {
            int s0 = __builtin_amdgcn_readfirstlane(csr_src[cbeg + i]);
            float p0 = readlane_f(p, i);
            acc0 += p0 * xl[s0 * H + lane];
        }
    }

    float o = (acc0 + acc1) / (l_run + 1e-16f) + bias[lane];
    out[d * H + lane] = o > 0.f ? o : expm1f(o);
}

// ---------------- pool: one block per graph, binary search on sorted batch ----------------
__global__ __launch_bounds__(256) void pool_mean_kernel(const float* __restrict__ h,
                                                        const int* __restrict__ batch,
                                                        float* __restrict__ gmean) {
    int g = blockIdx.x;
    int lo = 0, hi = N_NODES;
    while (lo < hi) { int mid = (lo + hi) >> 1; if (batch[mid] < g) lo = mid + 1; else hi = mid; }
    int start = lo;
    hi = N_NODES;
    while (lo < hi) { int mid = (lo + hi) >> 1; if (batch[mid] < g + 1) lo = mid + 1; else hi = mid; }
    int end = lo;

    int lane = threadIdx.x & 63;
    int w = threadIdx.x >> 6;
    float s = 0.f;
    for (int n = start + w; n < end; n += 4) s += h[n * H + lane];
    __shared__ float red[4][H];
    red[w][lane] = s;
    __syncthreads();
    if (w == 0) {
        float tot = red[0][lane] + red[1][lane] + red[2][lane] + red[3][lane];
        float c = (float)(end - start);
        gmean[g * H + lane] = tot / fmaxf(c, 1.f);
    }
}

// ---------------- head ----------------
__global__ void head_kernel(const float* __restrict__ gmean,
                            const float* __restrict__ fc1w, const float* __restrict__ fc1b,
                            const float* __restrict__ fc2w, const float* __restrict__ fc2b,
                            float* __restrict__ out) {
    __shared__ float g[H];
    __shared__ float f[FC];
    __shared__ float lg[NC];
    int b = blockIdx.x, t = threadIdx.x;
    if (t < H) g[t] = gmean[b * H + t];
    __syncthreads();
    float acc = fc1b[t];
    for (int k = 0; k < H; ++k) acc += g[k] * fc1w[k * FC + t];
    f[t] = fmaxf(acc, 0.f);
    __syncthreads();
    if (t < NC) {
        float a = fc2b[t];
        for (int k = 0; k < FC; ++k) a += f[k] * fc2w[k * NC + t];
        lg[t] = a;
    }
    __syncthreads();
    if (t < NC) {
        float mx = fmaxf(lg[0], lg[1]);
        float lse = mx + logf(expf(lg[0] - mx) + expf(lg[1] - mx));
        out[b * NC + t] = lg[t] - lse;
    }
}

extern "C" void kernel_launch(void* const* d_in, const int* in_sizes, int n_in,
                              void* d_out, int out_size, void* d_ws, size_t ws_size,
                              hipStream_t stream) {
    const float* x         = (const float*)d_in[0];
    const int*   edge_idx  = (const int*)d_in[1];
    const float* edge_attr = (const float*)d_in[2];
    const int*   batch     = (const int*)d_in[3];
    const float* Wl0  = (const float*)d_in[4];
    const float* bl0  = (const float*)d_in[5];
    const float* Wr0  = (const float*)d_in[6];
    const float* br0  = (const float*)d_in[7];
    const float* We0  = (const float*)d_in[8];
    const float* att0 = (const float*)d_in[9];
    const float* bias0= (const float*)d_in[10];
    const float* Wl1  = (const float*)d_in[11];
    const float* bl1  = (const float*)d_in[12];
    const float* Wr1  = (const float*)d_in[13];
    const float* br1  = (const float*)d_in[14];
    const float* We1  = (const float*)d_in[15];
    const float* att1 = (const float*)d_in[16];
    const float* bias1= (const float*)d_in[17];
    const float* fc1w = (const float*)d_in[18];
    const float* fc1b = (const float*)d_in[19];
    const float* fc2w = (const float*)d_in[20];
    const float* fc2b = (const float*)d_in[21];

    const int NH = N_NODES * H;
    float* A        = (float*)d_ws;            // xl [N,H]
    float* B        = A + NH;                  // xr [N,H]
    float* C        = B + NH;                  // layer output [N,H]
    int*   deg      = (int*)(C + NH);          // [N]
    int*   row_start= deg + N_NODES;           // [N+1]
    int*   cursor   = row_start + N_NODES + 1; // [N]
    int*   bsum     = cursor + N_NODES;        // [256]
    int*   boff     = bsum + 256;              // [256]
    int*   csr_src  = boff + 256;              // [E]
    int*   csr_eid  = csr_src + N_EDGES;       // [E]
    float* gmean    = (float*)(csr_eid + N_EDGES); // [G,H]
    size_t used = (size_t)(gmean + G_GRAPHS * H - (float*)d_ws) * sizeof(float);
    size_t ea_off = (used + 15) & ~(size_t)15;
    float4* csr_ea  = (float4*)((char*)d_ws + ea_off); // [E] float4
    bool use_ea = (ea_off + (size_t)N_EDGES * sizeof(float4)) <= ws_size;

    const int* src = edge_idx;
    const int* dst = edge_idx + N_EDGES;

    const int nodeBlocks = (NH + 255) / 256;
    const int edgeBlocks = (N_EDGES + 255) / 256;
    const int waveBlocks = (N_NODES * 64 + 255) / 256;

    // ---- CSR build ----
    hipMemsetAsync(deg, 0, (size_t)N_NODES * sizeof(int), stream);
    hist_kernel<<<edgeBlocks, 256, 0, stream>>>(dst, deg);
    scan_part_kernel<<<SCAN_BLOCKS, 256, 0, stream>>>(deg, bsum);
    scan_top_kernel<<<1, 256, 0, stream>>>(bsum, boff);
    scan_final_kernel<<<SCAN_BLOCKS, 256, 0, stream>>>(deg, boff, row_start, cursor);
    if (use_ea)
        scatter_kernel<true><<<edgeBlocks, 256, 0, stream>>>(src, dst, edge_attr, cursor, csr_src, csr_eid, csr_ea);
    else
        scatter_kernel<false><<<edgeBlocks, 256, 0, stream>>>(src, dst, edge_attr, cursor, csr_src, csr_eid, csr_ea);

    // ---- layer 0 ----
    proj_kernel<IN_CH><<<nodeBlocks, 256, 0, stream>>>(x, Wl0, bl0, Wr0, br0, A, B);
    if (use_ea)
        gat_gather_kernel<true><<<waveBlocks, 256, 0, stream>>>(row_start, csr_src, csr_eid, csr_ea, edge_attr, A, B, We0, att0, bias0, C);
    else
        gat_gather_kernel<false><<<waveBlocks, 256, 0, stream>>>(row_start, csr_src, csr_eid, csr_ea, edge_attr, A, B, We0, att0, bias0, C);

    // ---- layer 1 ----
    proj_kernel<H><<<nodeBlocks, 256, 0, stream>>>(C, Wl1, bl1, Wr1, br1, A, B);
    if (use_ea)
        gat_gather_kernel<true><<<waveBlocks, 256, 0, stream>>>(row_start, csr_src, csr_eid, csr_ea, edge_attr, A, B, We1, att1, bias1, C);
    else
        gat_gather_kernel<false><<<waveBlocks, 256, 0, stream>>>(row_start, csr_src, csr_eid, csr_ea, edge_attr, A, B, We1, att1, bias1, C);

    // ---- pool + head ----
    pool_mean_kernel<<<G_GRAPHS, 256, 0, stream>>>(C, batch, gmean);
    head_kernel<<<G_GRAPHS, FC, 0, stream>>>(gmean, fc1w, fc1b, fc2w, fc2b, (float*)d_out);
}

// Round 6
// 599.471 us; speedup vs baseline: 3.0763x; 1.0089x over previous
//
#include <hip/hip_runtime.h>
#include <hip/hip_fp16.h>

#define N_NODES 50000
#define N_EDGES 1600000
#define H 64
#define IN_CH 7
#define EDIM 4
#define G_GRAPHS 256
#define FC 128
#define NC 2
#define SLOPE 0.2f
#define SCAN_BLOCKS ((N_NODES + 255) / 256)   // 196

// ---------------- DPP wave-64 reductions ----------------
__device__ __forceinline__ float wave_sum_to63(float x) {
    x += __int_as_float(__builtin_amdgcn_update_dpp(0, __float_as_int(x), 0x111, 0xf, 0xf, true)); // row_shr:1
    x += __int_as_float(__builtin_amdgcn_update_dpp(0, __float_as_int(x), 0x112, 0xf, 0xf, true)); // row_shr:2
    x += __int_as_float(__builtin_amdgcn_update_dpp(0, __float_as_int(x), 0x114, 0xf, 0xf, true)); // row_shr:4
    x += __int_as_float(__builtin_amdgcn_update_dpp(0, __float_as_int(x), 0x118, 0xf, 0xf, true)); // row_shr:8
    x += __int_as_float(__builtin_amdgcn_update_dpp(0, __float_as_int(x), 0x142, 0xf, 0xf, true)); // row_bcast:15
    x += __int_as_float(__builtin_amdgcn_update_dpp(0, __float_as_int(x), 0x143, 0xf, 0xf, true)); // row_bcast:31
    return x;
}
__device__ __forceinline__ float wave_max_to63(float x) {
    int xi = __float_as_int(x);
    x = fmaxf(x, __int_as_float(__builtin_amdgcn_update_dpp(xi, xi, 0x111, 0xf, 0xf, false))); xi = __float_as_int(x);
    x = fmaxf(x, __int_as_float(__builtin_amdgcn_update_dpp(xi, xi, 0x112, 0xf, 0xf, false))); xi = __float_as_int(x);
    x = fmaxf(x, __int_as_float(__builtin_amdgcn_update_dpp(xi, xi, 0x114, 0xf, 0xf, false))); xi = __float_as_int(x);
    x = fmaxf(x, __int_as_float(__builtin_amdgcn_update_dpp(xi, xi, 0x118, 0xf, 0xf, false))); xi = __float_as_int(x);
    x = fmaxf(x, __int_as_float(__builtin_amdgcn_update_dpp(xi, xi, 0x142, 0xf, 0xf, false))); xi = __float_as_int(x);
    x = fmaxf(x, __int_as_float(__builtin_amdgcn_update_dpp(xi, xi, 0x143, 0xf, 0xf, false)));
    return x;
}
__device__ __forceinline__ float lane63_bcast(float x) {
    return __int_as_float(__builtin_amdgcn_readlane(__float_as_int(x), 63));
}
__device__ __forceinline__ float readlane_f(float x, int i) {
    return __int_as_float(__builtin_amdgcn_readlane(__float_as_int(x), i));
}

// ---------------- CSR build ----------------
// pass 1: deg histogram + within-dst rank (coalesced store)
__global__ void rank_kernel(const int* __restrict__ dst, int* __restrict__ deg,
                            int* __restrict__ rank) {
    int e = blockIdx.x * blockDim.x + threadIdx.x;
    if (e >= N_EDGES) return;
    rank[e] = atomicAdd(&deg[dst[e]], 1);
}

// 3-kernel parallel exclusive scan over deg[N]
__global__ void scan_part_kernel(const int* __restrict__ deg, int* __restrict__ bsum) {
    __shared__ int lds[256];
    int b = blockIdx.x, t = threadIdx.x;
    int idx = b * 256 + t;
    lds[t] = (idx < N_NODES) ? deg[idx] : 0;
    __syncthreads();
    for (int off = 128; off >= 1; off >>= 1) {
        if (t < off) lds[t] += lds[t + off];
        __syncthreads();
    }
    if (t == 0) bsum[b] = lds[0];
}

__global__ void scan_top_kernel(const int* __restrict__ bsum, int* __restrict__ boff) {
    __shared__ int lds[256];
    int t = threadIdx.x;
    int v = (t < SCAN_BLOCKS) ? bsum[t] : 0;
    lds[t] = v;
    __syncthreads();
    for (int off = 1; off < 256; off <<= 1) {
        int x = (t >= off) ? lds[t - off] : 0;
        __syncthreads();
        lds[t] += x;
        __syncthreads();
    }
    boff[t] = lds[t] - v;   // exclusive
}

__global__ void scan_final_kernel(const int* __restrict__ deg, const int* __restrict__ boff,
                                  int* __restrict__ row_start) {
    __shared__ int lds[256];
    int b = blockIdx.x, t = threadIdx.x;
    int idx = b * 256 + t;
    int v = (idx < N_NODES) ? deg[idx] : 0;
    lds[t] = v;
    __syncthreads();
    for (int off = 1; off < 256; off <<= 1) {
        int x = (t >= off) ? lds[t - off] : 0;
        __syncthreads();
        lds[t] += x;
        __syncthreads();
    }
    int excl = boff[b] + lds[t] - v;
    if (idx < N_NODES) {
        row_start[idx] = excl;
        if (idx == N_NODES - 1) row_start[N_NODES] = excl + v;
    }
}

// pass 2: non-atomic scatter of packed 16B entries {src, fp16x2(ea01), fp16x2(ea23), 0}
__global__ void scatter_kernel(const int* __restrict__ src, const int* __restrict__ dst,
                               const int* __restrict__ rank, const int* __restrict__ row_start,
                               const float* __restrict__ edge_attr,
                               int4* __restrict__ csr) {
    int e = blockIdx.x * blockDim.x + threadIdx.x;
    if (e >= N_EDGES) return;
    int d = dst[e];
    int slot = row_start[d] + rank[e];
    float4 ea = ((const float4*)edge_attr)[e];
    __half2 h01 = __floats2half2_rn(ea.x, ea.y);
    __half2 h23 = __floats2half2_rn(ea.z, ea.w);
    int4 ent;
    ent.x = src[e];
    ent.y = *reinterpret_cast<int*>(&h01);
    ent.z = *reinterpret_cast<int*>(&h23);
    ent.w = 0;
    csr[slot] = ent;
}

// ---------------- node projection ----------------
template <int K>
__global__ void proj_kernel(const float* __restrict__ xin,
                            const float* __restrict__ Wl, const float* __restrict__ bl,
                            const float* __restrict__ Wr, const float* __restrict__ br,
                            float* __restrict__ xl, float* __restrict__ xr) {
    int idx = blockIdx.x * blockDim.x + threadIdx.x;
    if (idx >= N_NODES * H) return;
    int n = idx >> 6;
    int h = idx & 63;
    const float* xi = xin + n * K;
    float al = bl[h], ar = br[h];
#pragma unroll
    for (int k = 0; k < K; ++k) {
        float xv = xi[k];
        al += xv * Wl[k * H + h];
        ar += xv * Wr[k * H + h];
    }
    xl[idx] = al;
    xr[idx] = ar;
}

// ---------------- fused GAT aggregation: one wave per dst node ----------------
// Per 64-edge chunk: one coalesced 16B load gives lane i edge i's {src, ea(fp16)};
// fp16->fp32 conversion amortized per chunk; per-edge values come from v_readlane
// (no broadcast VMEM loads on the critical path).
__global__ __launch_bounds__(256) void gat_gather_kernel(
        const int* __restrict__ row_start,
        const int4* __restrict__ csr,
        const float* __restrict__ xl, const float* __restrict__ xr,
        const float* __restrict__ We, const float* __restrict__ att,
        const float* __restrict__ bias,
        float* __restrict__ out) {
    int wave = (blockIdx.x * blockDim.x + threadIdx.x) >> 6;
    if (wave >= N_NODES) return;
    int lane = threadIdx.x & 63;
    int d = wave;
    float xr_d = xr[d * H + lane];
    float attv = att[lane];
    float we0 = We[lane], we1 = We[H + lane], we2 = We[2 * H + lane], we3 = We[3 * H + lane];
    int beg = __builtin_amdgcn_readfirstlane(row_start[d]);
    int end = __builtin_amdgcn_readfirstlane(row_start[d + 1]);

    float m_run = -INFINITY, l_run = 0.f;
    float acc0 = 0.f, acc1 = 0.f;

    for (int cbeg = beg; cbeg < end; cbeg += 64) {
        int n = min(64, end - cbeg);

        // ---- chunk staging: lane i holds edge (cbeg+i)'s data ----
        int lidx = cbeg + lane;
        lidx = lidx < N_EDGES ? lidx : N_EDGES - 1;   // clamp tail OOB
        int4 ent = csr[lidx];
        int   msrc = ent.x;
        __half2 h01 = *reinterpret_cast<__half2*>(&ent.y);
        __half2 h23 = *reinterpret_cast<__half2*>(&ent.z);
        float meax = __low2float(h01), meay = __high2float(h01);
        float meaz = __low2float(h23), meaw = __high2float(h23);

        // ---- phase 0: scores; lane i ends up holding score of edge cbeg+i ----
        float scv = -INFINITY;
        int i = 0;
        for (; i + 4 <= n; i += 4) {
#pragma unroll
            for (int u = 0; u < 4; ++u) {
                int j = i + u;
                int s = __builtin_amdgcn_readlane(msrc, j);
                float eax = readlane_f(meax, j), eay = readlane_f(meay, j);
                float eaz = readlane_f(meaz, j), eaw = readlane_f(meaw, j);
                float v = xl[s * H + lane] + xr_d + eax * we0 + eay * we1 + eaz * we2 + eaw * we3;
                v = v > 0.f ? v : SLOPE * v;
                float r = wave_sum_to63(v * attv);
                float sv = lane63_bcast(r);
                scv = (lane == j) ? sv : scv;
            }
        }
        for (; i < n; ++i) {
            int s = __builtin_amdgcn_readlane(msrc, i);
            float eax = readlane_f(meax, i), eay = readlane_f(meay, i);
            float eaz = readlane_f(meaz, i), eaw = readlane_f(meaw, i);
            float v = xl[s * H + lane] + xr_d + eax * we0 + eay * we1 + eaz * we2 + eaw * we3;
            v = v > 0.f ? v : SLOPE * v;
            float r = wave_sum_to63(v * attv);
            float sv = lane63_bcast(r);
            scv = (lane == i) ? sv : scv;
        }

        // ---- phase 1: lane-parallel softmax pieces ----
        float m_chunk = lane63_bcast(wave_max_to63(scv));
        float m_new = fmaxf(m_run, m_chunk);
        float corr = __expf(m_run - m_new);   // first chunk: exp(-inf)=0
        float p = __expf(scv - m_new);        // lanes >= n: exp(-inf)=0
        float psum = lane63_bcast(wave_sum_to63(p));
        l_run = l_run * corr + psum;
        acc0 *= corr;
        acc1 *= corr;
        m_run = m_new;

        // ---- phase 2: weighted accumulation (independent iterations) ----
        i = 0;
        for (; i + 4 <= n; i += 4) {
            int s0 = __builtin_amdgcn_readlane(msrc, i + 0);
            int s1 = __builtin_amdgcn_readlane(msrc, i + 1);
            int s2 = __builtin_amdgcn_readlane(msrc, i + 2);
            int s3 = __builtin_amdgcn_readlane(msrc, i + 3);
            float p0 = readlane_f(p, i + 0);
            float p1 = readlane_f(p, i + 1);
            float p2 = readlane_f(p, i + 2);
            float p3 = readlane_f(p, i + 3);
            acc0 += p0 * xl[s0 * H + lane];
            acc1 += p1 * xl[s1 * H + lane];
            acc0 += p2 * xl[s2 * H + lane];
            acc1 += p3 * xl[s3 * H + lane];
        }
        for (; i < n; ++i) {
            int s0 = __builtin_amdgcn_readlane(msrc, i);
            float p0 = readlane_f(p, i);
            acc0 += p0 * xl[s0 * H + lane];
        }
    }

    float o = (acc0 + acc1) / (l_run + 1e-16f) + bias[lane];
    out[d * H + lane] = o > 0.f ? o : expm1f(o);
}

// ---------------- pool: one block per graph, binary search on sorted batch ----------------
__global__ __launch_bounds__(256) void pool_mean_kernel(const float* __restrict__ h,
                                                        const int* __restrict__ batch,
                                                        float* __restrict__ gmean) {
    int g = blockIdx.x;
    int lo = 0, hi = N_NODES;
    while (lo < hi) { int mid = (lo + hi) >> 1; if (batch[mid] < g) lo = mid + 1; else hi = mid; }
    int start = lo;
    hi = N_NODES;
    while (lo < hi) { int mid = (lo + hi) >> 1; if (batch[mid] < g + 1) lo = mid + 1; else hi = mid; }
    int end = lo;

    int lane = threadIdx.x & 63;
    int w = threadIdx.x >> 6;
    float s = 0.f;
    for (int n = start + w; n < end; n += 4) s += h[n * H + lane];
    __shared__ float red[4][H];
    red[w][lane] = s;
    __syncthreads();
    if (w == 0) {
        float tot = red[0][lane] + red[1][lane] + red[2][lane] + red[3][lane];
        float c = (float)(end - start);
        gmean[g * H + lane] = tot / fmaxf(c, 1.f);
    }
}

// ---------------- head ----------------
__global__ void head_kernel(const float* __restrict__ gmean,
                            const float* __restrict__ fc1w, const float* __restrict__ fc1b,
                            const float* __restrict__ fc2w, const float* __restrict__ fc2b,
                            float* __restrict__ out) {
    __shared__ float g[H];
    __shared__ float f[FC];
    __shared__ float lg[NC];
    int b = blockIdx.x, t = threadIdx.x;
    if (t < H) g[t] = gmean[b * H + t];
    __syncthreads();
    float acc = fc1b[t];
    for (int k = 0; k < H; ++k) acc += g[k] * fc1w[k * FC + t];
    f[t] = fmaxf(acc, 0.f);
    __syncthreads();
    if (t < NC) {
        float a = fc2b[t];
        for (int k = 0; k < FC; ++k) a += f[k] * fc2w[k * NC + t];
        lg[t] = a;
    }
    __syncthreads();
    if (t < NC) {
        float mx = fmaxf(lg[0], lg[1]);
        float lse = mx + logf(expf(lg[0] - mx) + expf(lg[1] - mx));
        out[b * NC + t] = lg[t] - lse;
    }
}

extern "C" void kernel_launch(void* const* d_in, const int* in_sizes, int n_in,
                              void* d_out, int out_size, void* d_ws, size_t ws_size,
                              hipStream_t stream) {
    const float* x         = (const float*)d_in[0];
    const int*   edge_idx  = (const int*)d_in[1];
    const float* edge_attr = (const float*)d_in[2];
    const int*   batch     = (const int*)d_in[3];
    const float* Wl0  = (const float*)d_in[4];
    const float* bl0  = (const float*)d_in[5];
    const float* Wr0  = (const float*)d_in[6];
    const float* br0  = (const float*)d_in[7];
    const float* We0  = (const float*)d_in[8];
    const float* att0 = (const float*)d_in[9];
    const float* bias0= (const float*)d_in[10];
    const float* Wl1  = (const float*)d_in[11];
    const float* bl1  = (const float*)d_in[12];
    const float* Wr1  = (const float*)d_in[13];
    const float* br1  = (const float*)d_in[14];
    const float* We1  = (const float*)d_in[15];
    const float* att1 = (const float*)d_in[16];
    const float* bias1= (const float*)d_in[17];
    const float* fc1w = (const float*)d_in[18];
    const float* fc1b = (const float*)d_in[19];
    const float* fc2w = (const float*)d_in[20];
    const float* fc2b = (const float*)d_in[21];

    const int NH = N_NODES * H;
    float* A        = (float*)d_ws;            // xl [N,H]  (also rank[] during CSR build)
    float* B        = A + NH;                  // xr [N,H]
    float* C        = B + NH;                  // layer output [N,H]
    int*   deg      = (int*)(C + NH);          // [N]
    int*   row_start= deg + N_NODES;           // [N+1]
    int*   bsum     = row_start + N_NODES + 1; // [256]
    int*   boff     = bsum + 256;              // [256]
    char*  after    = (char*)(boff + 256);
    size_t csr_off  = (((size_t)(after - (char*)d_ws)) + 15) & ~(size_t)15;
    int4*  csr      = (int4*)((char*)d_ws + csr_off);   // [E] packed 16B
    float* gmean    = (float*)((char*)csr + (size_t)N_EDGES * sizeof(int4)); // [G,H]
    int*   rank     = (int*)A;                 // [E] — dead before proj0 writes A

    const int* src = edge_idx;
    const int* dst = edge_idx + N_EDGES;

    const int nodeBlocks = (NH + 255) / 256;
    const int edgeBlocks = (N_EDGES + 255) / 256;
    const int waveBlocks = (N_NODES * 64 + 255) / 256;

    // ---- CSR build (rank -> scan -> scatter; no cursor, no separate hist) ----
    (void)hipMemsetAsync(deg, 0, (size_t)N_NODES * sizeof(int), stream);
    rank_kernel<<<edgeBlocks, 256, 0, stream>>>(dst, deg, rank);
    scan_part_kernel<<<SCAN_BLOCKS, 256, 0, stream>>>(deg, bsum);
    scan_top_kernel<<<1, 256, 0, stream>>>(bsum, boff);
    scan_final_kernel<<<SCAN_BLOCKS, 256, 0, stream>>>(deg, boff, row_start);
    scatter_kernel<<<edgeBlocks, 256, 0, stream>>>(src, dst, rank, row_start, edge_attr, csr);

    // ---- layer 0 ----
    proj_kernel<IN_CH><<<nodeBlocks, 256, 0, stream>>>(x, Wl0, bl0, Wr0, br0, A, B);
    gat_gather_kernel<<<waveBlocks, 256, 0, stream>>>(row_start, csr, A, B, We0, att0, bias0, C);

    // ---- layer 1 ----
    proj_kernel<H><<<nodeBlocks, 256, 0, stream>>>(C, Wl1, bl1, Wr1, br1, A, B);
    gat_gather_kernel<<<waveBlocks, 256, 0, stream>>>(row_start, csr, A, B, We1, att1, bias1, C);

    // ---- pool + head ----
    pool_mean_kernel<<<G_GRAPHS, 256, 0, stream>>>(C, batch, gmean);
    head_kernel<<<G_GRAPHS, FC, 0, stream>>>(gmean, fc1w, fc1b, fc2w, fc2b, (float*)d_out);
}

// Round 7
// 542.907 us; speedup vs baseline: 3.3968x; 1.1042x over previous
//
#include <hip/hip_runtime.h>
#include <hip/hip_fp16.h>

#define N_NODES 50000
#define N_EDGES 1600000
#define H 64
#define IN_CH 7
#define EDIM 4
#define G_GRAPHS 256
#define FC 128
#define NC 2
#define SLOPE 0.2f
#define SCAN_BLOCKS ((N_NODES + 255) / 256)   // 196

// ---------------- DPP wave-64 reductions ----------------
__device__ __forceinline__ float wave_sum_to63(float x) {
    x += __int_as_float(__builtin_amdgcn_update_dpp(0, __float_as_int(x), 0x111, 0xf, 0xf, true)); // row_shr:1
    x += __int_as_float(__builtin_amdgcn_update_dpp(0, __float_as_int(x), 0x112, 0xf, 0xf, true)); // row_shr:2
    x += __int_as_float(__builtin_amdgcn_update_dpp(0, __float_as_int(x), 0x114, 0xf, 0xf, true)); // row_shr:4
    x += __int_as_float(__builtin_amdgcn_update_dpp(0, __float_as_int(x), 0x118, 0xf, 0xf, true)); // row_shr:8
    x += __int_as_float(__builtin_amdgcn_update_dpp(0, __float_as_int(x), 0x142, 0xf, 0xf, true)); // row_bcast:15
    x += __int_as_float(__builtin_amdgcn_update_dpp(0, __float_as_int(x), 0x143, 0xf, 0xf, true)); // row_bcast:31
    return x;
}
__device__ __forceinline__ float wave_max_to63(float x) {
    int xi = __float_as_int(x);
    x = fmaxf(x, __int_as_float(__builtin_amdgcn_update_dpp(xi, xi, 0x111, 0xf, 0xf, false))); xi = __float_as_int(x);
    x = fmaxf(x, __int_as_float(__builtin_amdgcn_update_dpp(xi, xi, 0x112, 0xf, 0xf, false))); xi = __float_as_int(x);
    x = fmaxf(x, __int_as_float(__builtin_amdgcn_update_dpp(xi, xi, 0x114, 0xf, 0xf, false))); xi = __float_as_int(x);
    x = fmaxf(x, __int_as_float(__builtin_amdgcn_update_dpp(xi, xi, 0x118, 0xf, 0xf, false))); xi = __float_as_int(x);
    x = fmaxf(x, __int_as_float(__builtin_amdgcn_update_dpp(xi, xi, 0x142, 0xf, 0xf, false))); xi = __float_as_int(x);
    x = fmaxf(x, __int_as_float(__builtin_amdgcn_update_dpp(xi, xi, 0x143, 0xf, 0xf, false)));
    return x;
}
__device__ __forceinline__ float lane63_bcast(float x) {
    return __int_as_float(__builtin_amdgcn_readlane(__float_as_int(x), 63));
}
__device__ __forceinline__ float readlane_f(float x, int i) {
    return __int_as_float(__builtin_amdgcn_readlane(__float_as_int(x), i));
}

// ---------------- CSR build ----------------
// pass 1: deg histogram + within-dst rank (coalesced store)
__global__ void rank_kernel(const int* __restrict__ dst, int* __restrict__ deg,
                            int* __restrict__ rank) {
    int e = blockIdx.x * blockDim.x + threadIdx.x;
    if (e >= N_EDGES) return;
    rank[e] = atomicAdd(&deg[dst[e]], 1);
}

// 3-kernel parallel exclusive scan over deg[N]
__global__ void scan_part_kernel(const int* __restrict__ deg, int* __restrict__ bsum) {
    __shared__ int lds[256];
    int b = blockIdx.x, t = threadIdx.x;
    int idx = b * 256 + t;
    lds[t] = (idx < N_NODES) ? deg[idx] : 0;
    __syncthreads();
    for (int off = 128; off >= 1; off >>= 1) {
        if (t < off) lds[t] += lds[t + off];
        __syncthreads();
    }
    if (t == 0) bsum[b] = lds[0];
}

__global__ void scan_top_kernel(const int* __restrict__ bsum, int* __restrict__ boff) {
    __shared__ int lds[256];
    int t = threadIdx.x;
    int v = (t < SCAN_BLOCKS) ? bsum[t] : 0;
    lds[t] = v;
    __syncthreads();
    for (int off = 1; off < 256; off <<= 1) {
        int x = (t >= off) ? lds[t - off] : 0;
        __syncthreads();
        lds[t] += x;
        __syncthreads();
    }
    boff[t] = lds[t] - v;   // exclusive
}

__global__ void scan_final_kernel(const int* __restrict__ deg, const int* __restrict__ boff,
                                  int* __restrict__ row_start) {
    __shared__ int lds[256];
    int b = blockIdx.x, t = threadIdx.x;
    int idx = b * 256 + t;
    int v = (idx < N_NODES) ? deg[idx] : 0;
    lds[t] = v;
    __syncthreads();
    for (int off = 1; off < 256; off <<= 1) {
        int x = (t >= off) ? lds[t - off] : 0;
        __syncthreads();
        lds[t] += x;
        __syncthreads();
    }
    int excl = boff[b] + lds[t] - v;
    if (idx < N_NODES) {
        row_start[idx] = excl;
        if (idx == N_NODES - 1) row_start[N_NODES] = excl + v;
    }
}

// pass 2: non-atomic scatter of packed 16B entries {src, fp16x2(ea01), fp16x2(ea23), 0}
__global__ void scatter_kernel(const int* __restrict__ src, const int* __restrict__ dst,
                               const int* __restrict__ rank, const int* __restrict__ row_start,
                               const float* __restrict__ edge_attr,
                               int4* __restrict__ csr) {
    int e = blockIdx.x * blockDim.x + threadIdx.x;
    if (e >= N_EDGES) return;
    int d = dst[e];
    int slot = row_start[d] + rank[e];
    float4 ea = ((const float4*)edge_attr)[e];
    __half2 h01 = __floats2half2_rn(ea.x, ea.y);
    __half2 h23 = __floats2half2_rn(ea.z, ea.w);
    int4 ent;
    ent.x = src[e];
    ent.y = *reinterpret_cast<int*>(&h01);
    ent.z = *reinterpret_cast<int*>(&h23);
    ent.w = 0;
    csr[slot] = ent;
}

// ---------------- node projection ----------------
template <int K>
__global__ void proj_kernel(const float* __restrict__ xin,
                            const float* __restrict__ Wl, const float* __restrict__ bl,
                            const float* __restrict__ Wr, const float* __restrict__ br,
                            float* __restrict__ xl, float* __restrict__ xr) {
    int idx = blockIdx.x * blockDim.x + threadIdx.x;
    if (idx >= N_NODES * H) return;
    int n = idx >> 6;
    int h = idx & 63;
    const float* xi = xin + n * K;
    float al = bl[h], ar = br[h];
#pragma unroll
    for (int k = 0; k < K; ++k) {
        float xv = xi[k];
        al += xv * Wl[k * H + h];
        ar += xv * Wr[k * H + h];
    }
    xl[idx] = al;
    xr[idx] = ar;
}

// ---------------- fused GAT aggregation: one wave per dst node ----------------
// Per edge: one wave-uniform-address 16B load (scalarizes to s_load_dwordx4),
// readfirstlane only on src (saddr-form xl gather). No per-edge readlane fan-out.
__device__ __forceinline__ float edge_v(const int4& ent, const float* __restrict__ xl,
                                        float xr_d, float we0, float we1, float we2, float we3,
                                        int lane, int& s_out) {
    int s = __builtin_amdgcn_readfirstlane(ent.x);
    s_out = s;
    __half2 h01 = *reinterpret_cast<const __half2*>(&ent.y);
    __half2 h23 = *reinterpret_cast<const __half2*>(&ent.z);
    float2 ea01 = __half22float2(h01);
    float2 ea23 = __half22float2(h23);
    float v = xl[s * H + lane] + xr_d;
    v += ea01.x * we0 + ea01.y * we1 + ea23.x * we2 + ea23.y * we3;
    return fmaxf(v, SLOPE * v);   // leaky_relu, slope<1
}

__global__ __launch_bounds__(256) void gat_gather_kernel(
        const int* __restrict__ row_start,
        const int4* __restrict__ csr,
        const float* __restrict__ xl, const float* __restrict__ xr,
        const float* __restrict__ We, const float* __restrict__ att,
        const float* __restrict__ bias,
        float* __restrict__ out) {
    int wave = (blockIdx.x * blockDim.x + threadIdx.x) >> 6;
    if (wave >= N_NODES) return;
    int lane = threadIdx.x & 63;
    int d = wave;
    float xr_d = xr[d * H + lane];
    float attv = att[lane];
    float we0 = We[lane], we1 = We[H + lane], we2 = We[2 * H + lane], we3 = We[3 * H + lane];
    int beg = __builtin_amdgcn_readfirstlane(row_start[d]);
    int end = __builtin_amdgcn_readfirstlane(row_start[d + 1]);

    float m_run = -INFINITY, l_run = 0.f;
    float acc0 = 0.f, acc1 = 0.f;

    for (int cbeg = beg; cbeg < end; cbeg += 64) {
        int n = min(64, end - cbeg);

        // ---- phase 0: scores; lane i ends up holding score of edge cbeg+i ----
        float scv = -INFINITY;
        int i = 0;
        for (; i + 4 <= n; i += 4) {
            int4 e0 = csr[cbeg + i + 0];
            int4 e1 = csr[cbeg + i + 1];
            int4 e2 = csr[cbeg + i + 2];
            int4 e3 = csr[cbeg + i + 3];
            int s0, s1, s2, s3;
            float v0 = edge_v(e0, xl, xr_d, we0, we1, we2, we3, lane, s0);
            float v1 = edge_v(e1, xl, xr_d, we0, we1, we2, we3, lane, s1);
            float v2 = edge_v(e2, xl, xr_d, we0, we1, we2, we3, lane, s2);
            float v3 = edge_v(e3, xl, xr_d, we0, we1, we2, we3, lane, s3);
            float r0 = wave_sum_to63(v0 * attv);
            float r1 = wave_sum_to63(v1 * attv);
            float r2 = wave_sum_to63(v2 * attv);
            float r3 = wave_sum_to63(v3 * attv);
            float b0 = lane63_bcast(r0), b1 = lane63_bcast(r1), b2 = lane63_bcast(r2), b3 = lane63_bcast(r3);
            scv = (lane == i + 0) ? b0 : scv;
            scv = (lane == i + 1) ? b1 : scv;
            scv = (lane == i + 2) ? b2 : scv;
            scv = (lane == i + 3) ? b3 : scv;
        }
        for (; i < n; ++i) {
            int4 e0 = csr[cbeg + i];
            int s0;
            float v0 = edge_v(e0, xl, xr_d, we0, we1, we2, we3, lane, s0);
            float r0 = wave_sum_to63(v0 * attv);
            float b0 = lane63_bcast(r0);
            scv = (lane == i) ? b0 : scv;
        }

        // ---- phase 1: lane-parallel softmax pieces ----
        float m_chunk = lane63_bcast(wave_max_to63(scv));
        float m_new = fmaxf(m_run, m_chunk);
        float corr = __expf(m_run - m_new);   // first chunk: exp(-inf)=0
        float p = __expf(scv - m_new);        // lanes >= n: exp(-inf)=0
        float psum = lane63_bcast(wave_sum_to63(p));
        l_run = l_run * corr + psum;
        acc0 *= corr;
        acc1 *= corr;
        m_run = m_new;

        // ---- phase 2: weighted accumulation (independent iterations) ----
        i = 0;
        for (; i + 4 <= n; i += 4) {
            int s0 = __builtin_amdgcn_readfirstlane(csr[cbeg + i + 0].x);
            int s1 = __builtin_amdgcn_readfirstlane(csr[cbeg + i + 1].x);
            int s2 = __builtin_amdgcn_readfirstlane(csr[cbeg + i + 2].x);
            int s3 = __builtin_amdgcn_readfirstlane(csr[cbeg + i + 3].x);
            float p0 = readlane_f(p, i + 0);
            float p1 = readlane_f(p, i + 1);
            float p2 = readlane_f(p, i + 2);
            float p3 = readlane_f(p, i + 3);
            acc0 += p0 * xl[s0 * H + lane];
            acc1 += p1 * xl[s1 * H + lane];
            acc0 += p2 * xl[s2 * H + lane];
            acc1 += p3 * xl[s3 * H + lane];
        }
        for (; i < n; ++i) {
            int s0 = __builtin_amdgcn_readfirstlane(csr[cbeg + i].x);
            float p0 = readlane_f(p, i);
            acc0 += p0 * xl[s0 * H + lane];
        }
    }

    float o = (acc0 + acc1) / (l_run + 1e-16f) + bias[lane];
    out[d * H + lane] = o > 0.f ? o : expm1f(o);
}

// ---------------- pool: one block per graph, binary search on sorted batch ----------------
__global__ __launch_bounds__(256) void pool_mean_kernel(const float* __restrict__ h,
                                                        const int* __restrict__ batch,
                                                        float* __restrict__ gmean) {
    int g = blockIdx.x;
    int lo = 0, hi = N_NODES;
    while (lo < hi) { int mid = (lo + hi) >> 1; if (batch[mid] < g) lo = mid + 1; else hi = mid; }
    int start = lo;
    hi = N_NODES;
    while (lo < hi) { int mid = (lo + hi) >> 1; if (batch[mid] < g + 1) lo = mid + 1; else hi = mid; }
    int end = lo;

    int lane = threadIdx.x & 63;
    int w = threadIdx.x >> 6;
    float s = 0.f;
    for (int n = start + w; n < end; n += 4) s += h[n * H + lane];
    __shared__ float red[4][H];
    red[w][lane] = s;
    __syncthreads();
    if (w == 0) {
        float tot = red[0][lane] + red[1][lane] + red[2][lane] + red[3][lane];
        float c = (float)(end - start);
        gmean[g * H + lane] = tot / fmaxf(c, 1.f);
    }
}

// ---------------- head ----------------
__global__ void head_kernel(const float* __restrict__ gmean,
                            const float* __restrict__ fc1w, const float* __restrict__ fc1b,
                            const float* __restrict__ fc2w, const float* __restrict__ fc2b,
                            float* __restrict__ out) {
    __shared__ float g[H];
    __shared__ float f[FC];
    __shared__ float lg[NC];
    int b = blockIdx.x, t = threadIdx.x;
    if (t < H) g[t] = gmean[b * H + t];
    __syncthreads();
    float acc = fc1b[t];
    for (int k = 0; k < H; ++k) acc += g[k] * fc1w[k * FC + t];
    f[t] = fmaxf(acc, 0.f);
    __syncthreads();
    if (t < NC) {
        float a = fc2b[t];
        for (int k = 0; k < FC; ++k) a += f[k] * fc2w[k * NC + t];
        lg[t] = a;
    }
    __syncthreads();
    if (t < NC) {
        float mx = fmaxf(lg[0], lg[1]);
        float lse = mx + logf(expf(lg[0] - mx) + expf(lg[1] - mx));
        out[b * NC + t] = lg[t] - lse;
    }
}

extern "C" void kernel_launch(void* const* d_in, const int* in_sizes, int n_in,
                              void* d_out, int out_size, void* d_ws, size_t ws_size,
                              hipStream_t stream) {
    const float* x         = (const float*)d_in[0];
    const int*   edge_idx  = (const int*)d_in[1];
    const float* edge_attr = (const float*)d_in[2];
    const int*   batch     = (const int*)d_in[3];
    const float* Wl0  = (const float*)d_in[4];
    const float* bl0  = (const float*)d_in[5];
    const float* Wr0  = (const float*)d_in[6];
    const float* br0  = (const float*)d_in[7];
    const float* We0  = (const float*)d_in[8];
    const float* att0 = (const float*)d_in[9];
    const float* bias0= (const float*)d_in[10];
    const float* Wl1  = (const float*)d_in[11];
    const float* bl1  = (const float*)d_in[12];
    const float* Wr1  = (const float*)d_in[13];
    const float* br1  = (const float*)d_in[14];
    const float* We1  = (const float*)d_in[15];
    const float* att1 = (const float*)d_in[16];
    const float* bias1= (const float*)d_in[17];
    const float* fc1w = (const float*)d_in[18];
    const float* fc1b = (const float*)d_in[19];
    const float* fc2w = (const float*)d_in[20];
    const float* fc2b = (const float*)d_in[21];

    const int NH = N_NODES * H;
    float* A        = (float*)d_ws;            // xl [N,H]  (also rank[] during CSR build)
    float* B        = A + NH;                  // xr [N,H]
    float* C        = B + NH;                  // layer output [N,H]
    int*   deg      = (int*)(C + NH);          // [N]
    int*   row_start= deg + N_NODES;           // [N+1]
    int*   bsum     = row_start + N_NODES + 1; // [256]
    int*   boff     = bsum + 256;              // [256]
    char*  after    = (char*)(boff + 256);
    size_t csr_off  = (((size_t)(after - (char*)d_ws)) + 15) & ~(size_t)15;
    int4*  csr      = (int4*)((char*)d_ws + csr_off);   // [E] packed 16B
    float* gmean    = (float*)((char*)csr + (size_t)N_EDGES * sizeof(int4)); // [G,H]
    int*   rank     = (int*)A;                 // [E] — dead before proj0 writes A

    const int* src = edge_idx;
    const int* dst = edge_idx + N_EDGES;

    const int nodeBlocks = (NH + 255) / 256;
    const int edgeBlocks = (N_EDGES + 255) / 256;
    const int waveBlocks = (N_NODES * 64 + 255) / 256;

    // ---- CSR build (rank -> scan -> scatter; no cursor, no separate hist) ----
    (void)hipMemsetAsync(deg, 0, (size_t)N_NODES * sizeof(int), stream);
    rank_kernel<<<edgeBlocks, 256, 0, stream>>>(dst, deg, rank);
    scan_part_kernel<<<SCAN_BLOCKS, 256, 0, stream>>>(deg, bsum);
    scan_top_kernel<<<1, 256, 0, stream>>>(bsum, boff);
    scan_final_kernel<<<SCAN_BLOCKS, 256, 0, stream>>>(deg, boff, row_start);
    scatter_kernel<<<edgeBlocks, 256, 0, stream>>>(src, dst, rank, row_start, edge_attr, csr);

    // ---- layer 0 ----
    proj_kernel<IN_CH><<<nodeBlocks, 256, 0, stream>>>(x, Wl0, bl0, Wr0, br0, A, B);
    gat_gather_kernel<<<waveBlocks, 256, 0, stream>>>(row_start, csr, A, B, We0, att0, bias0, C);

    // ---- layer 1 ----
    proj_kernel<H><<<nodeBlocks, 256, 0, stream>>>(C, Wl1, bl1, Wr1, br1, A, B);
    gat_gather_kernel<<<waveBlocks, 256, 0, stream>>>(row_start, csr, A, B, We1, att1, bias1, C);

    // ---- pool + head ----
    pool_mean_kernel<<<G_GRAPHS, 256, 0, stream>>>(C, batch, gmean);
    head_kernel<<<G_GRAPHS, FC, 0, stream>>>(gmean, fc1w, fc1b, fc2w, fc2b, (float*)d_out);
}